// Round 9
// baseline (1229.778 us; speedup 1.0000x reference)
//
#include <hip/hip_runtime.h>
#include <hip/hip_bf16.h>
#include <stdint.h>

typedef unsigned long long u64;
typedef unsigned int u32;
typedef unsigned short u16;
typedef __attribute__((ext_vector_type(8))) short short8;
typedef __attribute__((ext_vector_type(16))) float float16;

#define NQ 2048
#define NT 65536
#define DIM 512
#define KNN 32
#define NC 100
#define NS 32               // slices (fallback paths), cand[q][slice][k]

// ---- fallback (R2) params ----
#define QT 32
#define SLICE (NT / NS)     // 2048
#define TT 256
#define KK 16
#define FCAP 32

// ---- prepass params (fp32, trains 0..2047 subsample) ----
#define PQT 32
#define PTT 256
#define PSLICE 512
#define NTPRE 2048

// ---- fused-mfma fallback params (R4, proven) ----
#define MQT 128
#define MTT 128
#define MBK 32
#define MSLICE 2048
#define SCAP 16
#define NTILES 256

// ---- filter-path params (R6, proven) ----
#define GCAP 4096           // per-query candidate capacity; exact-2048 seed admits ~1024±180 (17 sigma)

// ---- R9 gemm_filter geometry ----
#define GBUF 24576          // u16 elems per tile buffer (48 KB): Ah@0 Al@4096 Bh@8192 Bl@16384

// ---------------- row-norm kernel ----------------
__global__ void norm_kernel(const float* __restrict__ X, float* __restrict__ out, int nrows) {
    int row = blockIdx.x * 4 + (threadIdx.x >> 6);
    int lane = threadIdx.x & 63;
    if (row >= nrows) return;
    const float4* p = (const float4*)(X + (size_t)row * DIM);
    float4 a = p[lane];
    float4 b = p[lane + 64];
    float s = a.x*a.x + a.y*a.y + a.z*a.z + a.w*a.w
            + b.x*b.x + b.y*b.y + b.z*b.z + b.w*b.w;
    #pragma unroll
    for (int off = 32; off > 0; off >>= 1) s += __shfl_down(s, off, 64);
    if (lane == 0) out[row] = s;
}

// ---------------- bf16 hi/lo split ----------------
__global__ void split_kernel(const float* __restrict__ X, u16* __restrict__ H,
                             u16* __restrict__ L, int n4) {
    int i = blockIdx.x * 256 + threadIdx.x;
    if (i >= n4) return;
    float4 v = ((const float4*)X)[i];
    float f[4] = {v.x, v.y, v.z, v.w};
    u16 hh[4], ll[4];
    #pragma unroll
    for (int j = 0; j < 4; ++j) {
        union { __hip_bfloat16 b; u16 u; } cv;
        cv.b = __float2bfloat16(f[j]);
        hh[j] = cv.u;
        float hf = __bfloat162float(cv.b);
        cv.b = __float2bfloat16(f[j] - hf);
        ll[j] = cv.u;
    }
    ((ushort4*)H)[i] = make_ushort4(hh[0], hh[1], hh[2], hh[3]);
    ((ushort4*)L)[i] = make_ushort4(ll[0], ll[1], ll[2], ll[3]);
}

// ---------------- knn_pre: fp32 distances for trains 0..2047, written to Dpre --------------
__launch_bounds__(256, 2)
__global__ void knn_pre(const float* __restrict__ Xq, const float* __restrict__ Xt,
                        const float* __restrict__ q2, const float* __restrict__ t2,
                        float* __restrict__ Dpre) {
    __shared__ float sQ[KK][PQT];
    __shared__ float sT[KK][PTT];

    const int tid = threadIdx.x;
    const int q0 = blockIdx.x * PQT;
    const int t0p = blockIdx.y * PSLICE;
    const int tq4 = (tid >> 5) * 4;
    const int tt4 = (tid & 31) * 4;
    const int pg = tid & 63;
    const int kg = tid >> 6;
    const int qp = tid & 31;
    const int kq = tid >> 5;

    float qq[4];
    #pragma unroll
    for (int i = 0; i < 4; ++i) qq[i] = q2[q0 + tq4 + i];

    #pragma unroll 1
    for (int chunk = 0; chunk < PSLICE / PTT; ++chunk) {
        const int tbase = t0p + chunk * PTT;
        float acc[4][8];
        #pragma unroll
        for (int i = 0; i < 4; ++i)
            #pragma unroll
            for (int j = 0; j < 8; ++j) acc[i][j] = 0.f;

        #pragma unroll 1
        for (int k0 = 0; k0 < DIM; k0 += KK) {
            __syncthreads();   // protects sQ/sT reuse
            {
                const float* Tp = Xt + (size_t)(tbase + pg * 4) * DIM + k0 + kg * 4;
                float4 r0 = *(const float4*)(Tp);
                float4 r1 = *(const float4*)(Tp + DIM);
                float4 r2 = *(const float4*)(Tp + 2 * DIM);
                float4 r3 = *(const float4*)(Tp + 3 * DIM);
                *(float4*)&sT[kg * 4 + 0][pg * 4] = make_float4(r0.x, r1.x, r2.x, r3.x);
                *(float4*)&sT[kg * 4 + 1][pg * 4] = make_float4(r0.y, r1.y, r2.y, r3.y);
                *(float4*)&sT[kg * 4 + 2][pg * 4] = make_float4(r0.z, r1.z, r2.z, r3.z);
                *(float4*)&sT[kg * 4 + 3][pg * 4] = make_float4(r0.w, r1.w, r2.w, r3.w);
            }
            {
                float2 v = *(const float2*)(Xq + (size_t)(q0 + qp) * DIM + k0 + kq * 2);
                sQ[kq * 2 + 0][qp] = v.x;
                sQ[kq * 2 + 1][qp] = v.y;
            }
            __syncthreads();
            #pragma unroll
            for (int k = 0; k < KK; ++k) {
                float4 qv = *(const float4*)&sQ[k][tq4];
                float4 ta = *(const float4*)&sT[k][tt4];
                float4 tb = *(const float4*)&sT[k][128 + tt4];
                float qa[4] = {qv.x, qv.y, qv.z, qv.w};
                float tv[8] = {ta.x, ta.y, ta.z, ta.w, tb.x, tb.y, tb.z, tb.w};
                #pragma unroll
                for (int i = 0; i < 4; ++i)
                    #pragma unroll
                    for (int j = 0; j < 8; ++j)
                        acc[i][j] = fmaf(qa[i], tv[j], acc[i][j]);
            }
        }

        float t2v[8];
        #pragma unroll
        for (int j = 0; j < 4; ++j) {
            t2v[j]     = t2[tbase + tt4 + j];
            t2v[4 + j] = t2[tbase + 128 + tt4 + j];
        }
        #pragma unroll
        for (int i = 0; i < 4; ++i) {
            float4 lo, hi;
            lo.x = fmaxf(qq[i] - 2.f * acc[i][0] + t2v[0], 0.f);
            lo.y = fmaxf(qq[i] - 2.f * acc[i][1] + t2v[1], 0.f);
            lo.z = fmaxf(qq[i] - 2.f * acc[i][2] + t2v[2], 0.f);
            lo.w = fmaxf(qq[i] - 2.f * acc[i][3] + t2v[3], 0.f);
            hi.x = fmaxf(qq[i] - 2.f * acc[i][4] + t2v[4], 0.f);
            hi.y = fmaxf(qq[i] - 2.f * acc[i][5] + t2v[5], 0.f);
            hi.z = fmaxf(qq[i] - 2.f * acc[i][6] + t2v[6], 0.f);
            hi.w = fmaxf(qq[i] - 2.f * acc[i][7] + t2v[7], 0.f);
            *(float4*)&Dpre[(size_t)(q0 + tq4 + i) * NTPRE + tbase + tt4] = lo;
            *(float4*)&Dpre[(size_t)(q0 + tq4 + i) * NTPRE + tbase + 128 + tt4] = hi;
        }
    }
}

// ---------------- seed_topk: exact 32nd-smallest of Dpre row -> seed[q] -------------------
__launch_bounds__(64)
__global__ void seed_topk(const float* __restrict__ Dpre, u32* __restrict__ seed) {
    __shared__ u64 ll[64][KNN + 1];   // pad: stride 33 u64 -> 2-way banks only
    const int q = blockIdx.x;
    const int lane = threadIdx.x;
    #pragma unroll
    for (int j = 0; j <= KNN; ++j) ll[lane][j] = ~0ULL;
    const float* src = Dpre + (size_t)q * NTPRE;
    u64 kth = ~0ULL;
    for (int i = lane; i < NTPRE; i += 64) {
        u64 key = (u64)__float_as_uint(src[i]);
        if (key < kth) {
            int p = KNN - 1;
            while (p > 0 && ll[lane][p - 1] > key) { ll[lane][p] = ll[lane][p - 1]; --p; }
            ll[lane][p] = key;
            kth = ll[lane][KNN - 1];
        }
    }
    __syncthreads();
    int ptr = 0;
    u64 cur = ll[lane][0];
    u64 m = 0;
    for (int it = 0; it < KNN; ++it) {
        m = cur;
        #pragma unroll
        for (int off = 32; off > 0; off >>= 1) {
            u64 o = __shfl_xor(m, off, 64);
            m = (o < m) ? o : m;
        }
        u64 got = __ballot(cur == m);
        int w = __ffsll(got) - 1;
        if (lane == w) { ++ptr; cur = (ptr < KNN) ? ll[lane][ptr] : ~0ULL; }
    }
    if (lane == 0) seed[q] = (u32)m;   // 32nd smallest dist bits (exact over 2048 subsample)
}

// ---------------- async global->LDS 16B ----------------
__device__ __forceinline__ void gld16(const void* g, void* l) {
    __builtin_amdgcn_global_load_lds(
        (const __attribute__((address_space(1))) u32*)g,
        (__attribute__((address_space(3))) u32*)l, 16, 0, 0);
}

// ---------------- gemm_filter: 128q x 256t, 3-buffer counted-vmcnt pipeline (R9) ----------
// T3/T4 (m218, and the exact structure proven in knn_mfma R4): stage(T+2) -> compute(T) ->
// s_waitcnt vmcnt(6) [T+1's 6 loads/wave landed; T+2's 6 stay in flight] -> raw s_barrier.
// Loads get TWO windows (~1200+ cyc) of cover (L3-hit ~500 cyc). Windows/CU halve vs R8
// (256-wide T tile). 8 waves, wave w: m_off=(w>>2)*64, n_off=(w&3)*64. LDS 3x48K+2K=146K,
// 1 block/CU. XCD colocation remap retained (bijective: 4096 = 8*512).
__launch_bounds__(512, 1)
__global__ void gemm_filter(const u16* __restrict__ Qh, const u16* __restrict__ Ql,
                            const u16* __restrict__ Th, const u16* __restrict__ Tl,
                            const float* __restrict__ q2, const float* __restrict__ t2,
                            const u32* __restrict__ seed,
                            u32* __restrict__ gcnt, u64* __restrict__ glist) {
    __shared__ __align__(16) u16 tiles[3][GBUF];   // Ah[128][32]@0 Al@4096 Bh[256][32]@8192 Bl@16384
    __shared__ float sQ2L[128];
    __shared__ float sT2L[256];
    __shared__ u32 sSeed[128];

    const int tid = threadIdx.x;
    const int lane = tid & 63;
    const int wid = tid >> 6;             // 0..7
    const int bid = blockIdx.x + (int)(gridDim.x * blockIdx.y);   // x fastest (gridDim.x=16)
    const int wg  = ((bid & 7) << 9) + (bid >> 3);                // XCD-colocating remap (4096=8*512)
    const int q0g = (wg & 15) * 128;      // query base
    const int tb  = (wg >> 4) * 256;      // train base (32 consecutive y-tiles per XCD)
    const int m_off = (wid >> 2) * 64;    // 0,64
    const int n_off = (wid & 3) * 64;     // 0,64,128,192
    const int swz = ((lane >> 1) & 3) << 3;
    const int l4r = lane >> 2;
    const int l4c = (((lane & 3) ^ ((lane >> 3) & 3)) * 8);

    if (tid < 128) {
        sQ2L[tid] = q2[q0g + tid];
        sSeed[tid] = seed[q0g + tid] + 256u;   // admission threshold (+ulp margin)
    }
    if (tid < 256) sT2L[tid] = t2[tb + tid];

    float16 acc[2][2];
    acc[0][0] = (float16)(0.0f); acc[0][1] = (float16)(0.0f);
    acc[1][0] = (float16)(0.0f); acc[1][1] = (float16)(0.0f);

    // stage one 48 KB tile: 48 x (16 rows x 32 elems) units; wave w takes units w, w+8, ..., w+40
    // (exactly 6 gld16 per wave -> counted-vmcnt invariant).
    #define STAGE_TILE(BUF, K0)                                                         \
        do {                                                                            \
            _Pragma("unroll")                                                           \
            for (int s6 = 0; s6 < 6; ++s6) {                                            \
                const int ii = wid + s6 * 8;                                            \
                const u16* P; int rb, off;                                              \
                if (ii < 16) {                                                          \
                    P = (ii < 8) ? Qh : Ql; rb = q0g;                                   \
                    off = ((ii < 8) ? 0 : 4096) + (ii & 7) * 512;                       \
                    rb += (ii & 7) * 16;                                                \
                } else {                                                                \
                    const int jj = ii - 16;                                             \
                    P = (jj < 16) ? Th : Tl; rb = tb;                                   \
                    off = 8192 + ((jj < 16) ? 0 : 8192) + (jj & 15) * 512;              \
                    rb += (jj & 15) * 16;                                               \
                }                                                                       \
                gld16(P + (size_t)(rb + l4r) * DIM + (K0) + l4c,                        \
                      (u16*)tiles[BUF] + off);                                          \
            }                                                                           \
        } while (0)

    STAGE_TILE(0, 0);
    STAGE_TILE(1, MBK);
    __syncthreads();   // prologue drain: tiles 0,1 ready, sQ2L/sT2L/sSeed visible (vmcnt=0)

    int cb = 0;
    #pragma unroll 1
    for (int t = 0; t < DIM / MBK; ++t) {          // 16 windows
        const bool pf = (t + 2 < DIM / MBK);       // wave-uniform
        if (pf) {
            int bn = cb + 2; if (bn >= 3) bn -= 3;
            STAGE_TILE(bn, (t + 2) * MBK);
        }
        const u16* pAh = tiles[cb];
        const u16* pAl = pAh + 4096;
        const u16* pBh = pAh + 8192;
        const u16* pBl = pAh + 16384;
        __builtin_amdgcn_s_setprio(1);
        #pragma unroll
        for (int s = 0; s < 2; ++s) {
            const int kb = (s * 16 + (lane >> 5) * 8) ^ swz;
            short8 ah[2], al[2], bh[2], bl[2];
            #pragma unroll
            for (int mi = 0; mi < 2; ++mi) {
                int row = m_off + mi * 32 + (lane & 31);
                ah[mi] = *(const short8*)(const void*)&pAh[row * 32 + kb];
                al[mi] = *(const short8*)(const void*)&pAl[row * 32 + kb];
            }
            #pragma unroll
            for (int nj = 0; nj < 2; ++nj) {
                int row = n_off + nj * 32 + (lane & 31);
                bh[nj] = *(const short8*)(const void*)&pBh[row * 32 + kb];
                bl[nj] = *(const short8*)(const void*)&pBl[row * 32 + kb];
            }
            #pragma unroll
            for (int mi = 0; mi < 2; ++mi)
                #pragma unroll
                for (int nj = 0; nj < 2; ++nj) {
                    acc[mi][nj] = __builtin_amdgcn_mfma_f32_32x32x16_bf16(ah[mi], bh[nj], acc[mi][nj], 0, 0, 0);
                    acc[mi][nj] = __builtin_amdgcn_mfma_f32_32x32x16_bf16(ah[mi], bl[nj], acc[mi][nj], 0, 0, 0);
                    acc[mi][nj] = __builtin_amdgcn_mfma_f32_32x32x16_bf16(al[mi], bh[nj], acc[mi][nj], 0, 0, 0);
                }
        }
        __builtin_amdgcn_s_setprio(0);
        // counted wait: T+1's 6 loads (oldest) done, T+2's 6 in flight. All frag reads of
        // tiles[cb] consumed by MFMAs (compiler lgkmcnt) pre-barrier -> safe to DMA into
        // tiles[cb] (= stage of T+3) next window.
        if (pf) asm volatile("s_waitcnt vmcnt(6)" ::: "memory");
        else    asm volatile("s_waitcnt vmcnt(0)" ::: "memory");
        __builtin_amdgcn_s_barrier();
        __builtin_amdgcn_sched_barrier(0);
        ++cb; if (cb >= 3) cb = 0;
    }
    #undef STAGE_TILE

    // epilogue: rare filtered push (frag map: col=lane&31, row=(r&3)+8*(r>>2)+4*(lane>>5))
    #pragma unroll
    for (int mi = 0; mi < 2; ++mi)
        #pragma unroll
        for (int nj = 0; nj < 2; ++nj) {
            const int tcol_l = n_off + nj * 32 + (lane & 31);
            const float t2v = sT2L[tcol_l];
            #pragma unroll
            for (int r = 0; r < 16; ++r) {
                const int qrow_l = m_off + mi * 32 + (r & 3) + 8 * (r >> 2) + 4 * (lane >> 5);
                float d = fmaxf(sQ2L[qrow_l] - 2.0f * acc[mi][nj][r] + t2v, 0.0f);
                if (__float_as_uint(d) <= sSeed[qrow_l]) {
                    const int q = q0g + qrow_l;
                    u32 pos = atomicAdd(&gcnt[q], 1u);
                    if (pos < GCAP)
                        glist[(size_t)q * GCAP + pos] =
                            ((u64)__float_as_uint(d) << 16) | (u64)(u32)(tb + tcol_l);
                }
            }
        }
}

// ---------------- knn_topk: exact top-32 over candidate list + vote -> out ----------------
__launch_bounds__(64)
__global__ void knn_topk(const u64* __restrict__ glist, const u32* __restrict__ gcnt,
                         const int* __restrict__ y_train, int* __restrict__ out) {
    __shared__ u64 ll[64][KNN + 1];
    __shared__ u64 fin[KNN];
    __shared__ int counts[NC];
    const int q = blockIdx.x;
    const int lane = threadIdx.x;
    #pragma unroll
    for (int j = 0; j <= KNN; ++j) ll[lane][j] = ~0ULL;
    for (int i = lane; i < NC; i += 64) counts[i] = 0;
    u32 n = gcnt[q]; if (n > GCAP) n = GCAP;
    const u64* src = glist + (size_t)q * GCAP;
    u64 kth = ~0ULL;
    for (u32 i = lane; i < n; i += 64) {
        u64 key = src[i];
        if (key < kth) {
            int p = KNN - 1;
            while (p > 0 && ll[lane][p - 1] > key) { ll[lane][p] = ll[lane][p - 1]; --p; }
            ll[lane][p] = key;
            kth = ll[lane][KNN - 1];
        }
    }
    __syncthreads();
    int ptr = 0;
    u64 cur = ll[lane][0];
    for (int it = 0; it < KNN; ++it) {
        u64 m = cur;
        #pragma unroll
        for (int off = 32; off > 0; off >>= 1) {
            u64 o = __shfl_xor(m, off, 64);
            m = (o < m) ? o : m;
        }
        u64 got = __ballot(cur == m);
        int w = __ffsll(got) - 1;
        if (lane == 0) fin[it] = m;
        if (lane == w) { ++ptr; cur = (ptr < KNN) ? ll[lane][ptr] : ~0ULL; }
    }
    __syncthreads();
    if (lane < KNN) {
        int idx = (int)(fin[lane] & 0xFFFF);
        atomicAdd(&counts[y_train[idx]], 1);
    }
    __syncthreads();
    if (lane == 0) {
        int bestc = counts[0], bestl = 0;
        for (int c = 1; c < NC; ++c)
            if (counts[c] > bestc) { bestc = counts[c]; bestl = c; }
        out[q] = bestl;
    }
}

// ================= fallback machinery (R4 fused path + fp32 path), proven =================

__launch_bounds__(256, 2)
__global__ void knn_prepass(const float* __restrict__ Xq, const float* __restrict__ Xt,
                            const float* __restrict__ q2, const float* __restrict__ t2,
                            u32* __restrict__ seed) {
    __shared__ float sQ[KK][PQT];
    __shared__ float sT[KK][PTT];
    __shared__ float sD[PQT][PTT + 1];
    __shared__ u32 topk[PQT][KNN + 1];

    const int tid = threadIdx.x;
    const int q0 = blockIdx.x * PQT;
    const int t0p = blockIdx.y * PSLICE;
    const int tq4 = (tid >> 5) * 4;
    const int tt4 = (tid & 31) * 4;
    const int pg = tid & 63;
    const int kg = tid >> 6;
    const int qp = tid & 31;
    const int kq = tid >> 5;

    for (int i = tid; i < PQT * (KNN + 1); i += 256) ((u32*)topk)[i] = 0xFFFFFFFFu;
    u32 kth = 0xFFFFFFFFu;

    float qq[4];
    #pragma unroll
    for (int i = 0; i < 4; ++i) qq[i] = q2[q0 + tq4 + i];

    #pragma unroll 1
    for (int chunk = 0; chunk < PSLICE / PTT; ++chunk) {
        const int tbase = t0p + chunk * PTT;
        float acc[4][8];
        #pragma unroll
        for (int i = 0; i < 4; ++i)
            #pragma unroll
            for (int j = 0; j < 8; ++j) acc[i][j] = 0.f;

        #pragma unroll 1
        for (int k0 = 0; k0 < DIM; k0 += KK) {
            __syncthreads();
            {
                const float* Tp = Xt + (size_t)(tbase + pg * 4) * DIM + k0 + kg * 4;
                float4 r0 = *(const float4*)(Tp);
                float4 r1 = *(const float4*)(Tp + DIM);
                float4 r2 = *(const float4*)(Tp + 2 * DIM);
                float4 r3 = *(const float4*)(Tp + 3 * DIM);
                *(float4*)&sT[kg * 4 + 0][pg * 4] = make_float4(r0.x, r1.x, r2.x, r3.x);
                *(float4*)&sT[kg * 4 + 1][pg * 4] = make_float4(r0.y, r1.y, r2.y, r3.y);
                *(float4*)&sT[kg * 4 + 2][pg * 4] = make_float4(r0.z, r1.z, r2.z, r3.z);
                *(float4*)&sT[kg * 4 + 3][pg * 4] = make_float4(r0.w, r1.w, r2.w, r3.w);
            }
            {
                float2 v = *(const float2*)(Xq + (size_t)(q0 + qp) * DIM + k0 + kq * 2);
                sQ[kq * 2 + 0][qp] = v.x;
                sQ[kq * 2 + 1][qp] = v.y;
            }
            __syncthreads();
            #pragma unroll
            for (int k = 0; k < KK; ++k) {
                float4 qv = *(const float4*)&sQ[k][tq4];
                float4 ta = *(const float4*)&sT[k][tt4];
                float4 tb = *(const float4*)&sT[k][128 + tt4];
                float qa[4] = {qv.x, qv.y, qv.z, qv.w};
                float tv[8] = {ta.x, ta.y, ta.z, ta.w, tb.x, tb.y, tb.z, tb.w};
                #pragma unroll
                for (int i = 0; i < 4; ++i)
                    #pragma unroll
                    for (int j = 0; j < 8; ++j)
                        acc[i][j] = fmaf(qa[i], tv[j], acc[i][j]);
            }
        }

        #pragma unroll
        for (int i = 0; i < 4; ++i)
            #pragma unroll
            for (int j = 0; j < 8; ++j) {
                int t = (j < 4) ? (tt4 + j) : (128 + tt4 + (j - 4));
                sD[tq4 + i][t] = fmaxf((qq[i] - 2.f * acc[i][j]) + t2[tbase + t], 0.f);
            }
        __syncthreads();

        if (tid < PQT) {
            for (int t = 0; t < PTT; ++t) {
                u32 d = __float_as_uint(sD[tid][t]);
                if (d < kth) {
                    int p = KNN - 1;
                    while (p > 0 && topk[tid][p - 1] > d) {
                        topk[tid][p] = topk[tid][p - 1];
                        --p;
                    }
                    topk[tid][p] = d;
                    kth = topk[tid][KNN - 1];
                }
            }
        }
    }
    if (tid < PQT) atomicMin(&seed[q0 + tid], kth);
}

__device__ __forceinline__ void stage_tile(const u16* __restrict__ Qh, const u16* __restrict__ Ql,
                                           const u16* __restrict__ Th, const u16* __restrict__ Tl,
                                           u16* base, int q0, int tb, int k0, int wid, int lane) {
    const int l4r = lane >> 2;
    const int l4c = (((lane & 3) ^ ((lane >> 3) & 3)) * 8);
    #pragma unroll
    for (int u = 0; u < 4; ++u) {
        const u16* P = (u == 0) ? Qh : (u == 1) ? Ql : (u == 2) ? Th : Tl;
        const int r0 = (u < 2) ? q0 : tb;
        const u16* g = P + (size_t)(r0 + wid * 16 + l4r) * DIM + k0 + l4c;
        gld16(g, base + u * 4096 + wid * 512);
    }
}

__launch_bounds__(512, 1)
__global__ void knn_mfma(const u16* __restrict__ Qh, const u16* __restrict__ Ql,
                         const u16* __restrict__ Th, const u16* __restrict__ Tl,
                         const float* __restrict__ q2, const float* __restrict__ t2,
                         const u32* __restrict__ seed, u64* __restrict__ cand) {
    __shared__ __align__(16) u16 tiles[3][16384];
    __shared__ u32 topkD[MQT][KNN + 1];
    __shared__ u16 topkI[MQT][KNN + 1];
    __shared__ u64 sbuf[MQT][SCAP];
    __shared__ u64 kth64[MQT];
    __shared__ u32 cnt[MQT];
    __shared__ float sQ2[MQT];
    __shared__ float sT2[MTT];
    __shared__ int againF;

    const int tid = threadIdx.x;
    const int lane = tid & 63;
    const int wid = tid >> 6;
    const int q0 = blockIdx.y * MQT;
    const int s0 = blockIdx.x * MSLICE;
    const int m_off = (wid >> 2) * 64;
    const int n_off = (wid & 3) * 32;
    const int swz = ((lane >> 1) & 3) << 3;

    for (int i = tid; i < MQT * (KNN + 1); i += 512) {
        ((u32*)topkD)[i] = 0xFFFFFFFFu;
        ((u16*)topkI)[i] = 0xFFFFu;
    }
    u64 seedkey = ~0ULL;
    if (tid < MQT) {
        seedkey = ((u64)seed[q0 + tid] + 1) << 16;
        kth64[tid] = seedkey;
        cnt[tid] = 0u;
        sQ2[tid] = q2[q0 + tid];
    }
    if (tid == 0) againF = 0;

    stage_tile(Qh, Ql, Th, Tl, tiles[0], q0, s0, 0, wid, lane);
    stage_tile(Qh, Ql, Th, Tl, tiles[1], q0, s0, MBK, wid, lane);
    __syncthreads();

    int cb = 0;
    #pragma unroll 1
    for (int chunk = 0; chunk < MSLICE / MTT; ++chunk) {
        const int tb = s0 + chunk * MTT;
        float16 acc[2];
        acc[0] = (float16)(0.0f);
        acc[1] = (float16)(0.0f);

        #pragma unroll 1
        for (int t = 0; t < DIM / MBK; ++t) {
            const int Tn = chunk * 16 + t + 2;
            const bool pf = (Tn < NTILES);
            if (pf) {
                int bn = cb + 2; if (bn >= 3) bn -= 3;
                stage_tile(Qh, Ql, Th, Tl, tiles[bn], q0,
                           s0 + (Tn >> 4) * MTT, (Tn & 15) * MBK, wid, lane);
            }
            const u16* sAh = tiles[cb];
            const u16* sAl = sAh + 4096;
            const u16* sBh = sAh + 8192;
            const u16* sBl = sAh + 12288;
            #pragma unroll
            for (int s = 0; s < 2; ++s) {
                const int kb = (s * 16 + (lane >> 5) * 8) ^ swz;
                short8 ah[2], al[2];
                #pragma unroll
                for (int mi = 0; mi < 2; ++mi) {
                    int row = m_off + mi * 32 + (lane & 31);
                    ah[mi] = *(const short8*)(const void*)&sAh[row * MBK + kb];
                    al[mi] = *(const short8*)(const void*)&sAl[row * MBK + kb];
                }
                int brow = n_off + (lane & 31);
                short8 bh = *(const short8*)(const void*)&sBh[brow * MBK + kb];
                short8 bl = *(const short8*)(const void*)&sBl[brow * MBK + kb];
                #pragma unroll
                for (int mi = 0; mi < 2; ++mi) {
                    acc[mi] = __builtin_amdgcn_mfma_f32_32x32x16_bf16(ah[mi], bh, acc[mi], 0, 0, 0);
                    acc[mi] = __builtin_amdgcn_mfma_f32_32x32x16_bf16(ah[mi], bl, acc[mi], 0, 0, 0);
                    acc[mi] = __builtin_amdgcn_mfma_f32_32x32x16_bf16(al[mi], bh, acc[mi], 0, 0, 0);
                }
            }
            if (pf) asm volatile("s_waitcnt vmcnt(4)" ::: "memory");
            else    asm volatile("s_waitcnt vmcnt(0)" ::: "memory");
            __builtin_amdgcn_s_barrier();
            __builtin_amdgcn_sched_barrier(0);
            ++cb; if (cb >= 3) cb = 0;
        }

        if (tid < MTT) sT2[tid] = t2[tb + tid];
        __syncthreads();
        const float t2r = sT2[n_off + (lane & 31)];
        const int tcol = n_off + (lane & 31);

        u32 mask = 0;
        for (;;) {
            #pragma unroll
            for (int mi = 0; mi < 2; ++mi) {
                #pragma unroll
                for (int r = 0; r < 16; ++r) {
                    const int bit = mi * 16 + r;
                    if ((mask >> bit) & 1) continue;
                    const int qrow = m_off + mi * 32 + (r & 3) + 8 * (r >> 2) + 4 * (lane >> 5);
                    float d = fmaxf(sQ2[qrow] - 2.0f * acc[mi][r] + t2r, 0.0f);
                    u64 key = ((u64)__float_as_uint(d) << 16) | (u64)(u32)(tb + tcol);
                    if (key < kth64[qrow]) {
                        u32 pos = atomicAdd(&cnt[qrow], 1u);
                        if (pos < SCAP) { sbuf[qrow][pos] = key; mask |= (1u << bit); }
                    }
                }
            }
            __syncthreads();
            if (tid < MQT) {
                u32 n = cnt[tid];
                u32 m = n < SCAP ? n : SCAP;
                for (u32 e = 0; e < m; ++e) {
                    u64 key = sbuf[tid][e];
                    u64 last = ((u64)topkD[tid][KNN - 1] << 16) | topkI[tid][KNN - 1];
                    if (key < last) {
                        int p = KNN - 1;
                        while (p > 0) {
                            u64 prev = ((u64)topkD[tid][p - 1] << 16) | topkI[tid][p - 1];
                            if (prev > key) {
                                topkD[tid][p] = topkD[tid][p - 1];
                                topkI[tid][p] = topkI[tid][p - 1];
                                --p;
                            } else break;
                        }
                        topkD[tid][p] = (u32)(key >> 16);
                        topkI[tid][p] = (u16)(key & 0xFFFF);
                    }
                }
                u64 last = ((u64)topkD[tid][KNN - 1] << 16) | topkI[tid][KNN - 1];
                kth64[tid] = last < seedkey ? last : seedkey;
                if (n > SCAP) againF = 1;
                cnt[tid] = 0u;
            }
            __syncthreads();
            int go = againF;
            __syncthreads();
            if (tid == 0) againF = 0;
            if (!go) break;
            __syncthreads();
        }
    }

    __syncthreads();
    for (int i = tid; i < MQT * KNN; i += 512) {
        int q = i >> 5, k = i & 31;
        u64 key = ((u64)topkD[q][k] << 16) | topkI[q][k];
        cand[((size_t)(q0 + q) * NS + blockIdx.x) * KNN + k] = key;
    }
}

__launch_bounds__(256, 4)
__global__ void knn_part(const float* __restrict__ Xq, const float* __restrict__ Xt,
                         const float* __restrict__ q2, const float* __restrict__ t2,
                         u64* __restrict__ cand) {
    __shared__ float sQ[KK][QT];
    __shared__ float sT[KK][TT];
    __shared__ u64 topk[QT][KNN];
    __shared__ u64 buf[QT][FCAP];
    __shared__ u64 kth64[QT];
    __shared__ u32 cnt[QT];
    __shared__ int againF;

    const int tid = threadIdx.x;
    const int q0 = blockIdx.x * QT;
    const int t0 = blockIdx.y * SLICE;
    const int tq4 = (tid >> 5) * 4;
    const int tt4 = (tid & 31) * 4;
    const int pg = tid & 63;
    const int kg = tid >> 6;
    const int qp = tid & 31;
    const int kq = tid >> 5;

    for (int i = tid; i < QT * KNN; i += 256) ((u64*)topk)[i] = ~0ULL;
    if (tid < QT) { kth64[tid] = ~0ULL; cnt[tid] = 0u; }
    if (tid == 0) againF = 0;

    float qq[4];
    #pragma unroll
    for (int i = 0; i < 4; ++i) qq[i] = q2[q0 + tq4 + i];

    #pragma unroll 1
    for (int chunk = 0; chunk < SLICE / TT; ++chunk) {
        const int tbase = t0 + chunk * TT;
        float acc[4][8];
        #pragma unroll
        for (int i = 0; i < 4; ++i)
            #pragma unroll
            for (int j = 0; j < 8; ++j) acc[i][j] = 0.f;

        #pragma unroll 1
        for (int k0 = 0; k0 < DIM; k0 += KK) {
            __syncthreads();
            {
                const float* Tp = Xt + (size_t)(tbase + pg * 4) * DIM + k0 + kg * 4;
                float4 r0 = *(const float4*)(Tp);
                float4 r1 = *(const float4*)(Tp + DIM);
                float4 r2 = *(const float4*)(Tp + 2 * DIM);
                float4 r3 = *(const float4*)(Tp + 3 * DIM);
                *(float4*)&sT[kg * 4 + 0][pg * 4] = make_float4(r0.x, r1.x, r2.x, r3.x);
                *(float4*)&sT[kg * 4 + 1][pg * 4] = make_float4(r0.y, r1.y, r2.y, r3.y);
                *(float4*)&sT[kg * 4 + 2][pg * 4] = make_float4(r0.z, r1.z, r2.z, r3.z);
                *(float4*)&sT[kg * 4 + 3][pg * 4] = make_float4(r0.w, r1.w, r2.w, r3.w);
            }
            {
                float2 v = *(const float2*)(Xq + (size_t)(q0 + qp) * DIM + k0 + kq * 2);
                sQ[kq * 2 + 0][qp] = v.x;
                sQ[kq * 2 + 1][qp] = v.y;
            }
            __syncthreads();
            #pragma unroll
            for (int k = 0; k < KK; ++k) {
                float4 qv = *(const float4*)&sQ[k][tq4];
                float4 ta = *(const float4*)&sT[k][tt4];
                float4 tb = *(const float4*)&sT[k][128 + tt4];
                float qa[4] = {qv.x, qv.y, qv.z, qv.w};
                float tv[8] = {ta.x, ta.y, ta.z, ta.w, tb.x, tb.y, tb.z, tb.w};
                #pragma unroll
                for (int i = 0; i < 4; ++i)
                    #pragma unroll
                    for (int j = 0; j < 8; ++j)
                        acc[i][j] = fmaf(qa[i], tv[j], acc[i][j]);
            }
        }

        float t2v[8];
        #pragma unroll
        for (int j = 0; j < 4; ++j) {
            t2v[j]     = t2[tbase + tt4 + j];
            t2v[4 + j] = t2[tbase + 128 + tt4 + j];
        }
        #pragma unroll
        for (int i = 0; i < 4; ++i)
            #pragma unroll
            for (int j = 0; j < 8; ++j)
                acc[i][j] = fmaxf((qq[i] - 2.f * acc[i][j]) + t2v[j], 0.f);

        unsigned mask = 0;
        for (;;) {
            u64 kv[4];
            #pragma unroll
            for (int i = 0; i < 4; ++i) kv[i] = kth64[tq4 + i];
            #pragma unroll
            for (int i = 0; i < 4; ++i) {
                #pragma unroll
                for (int j = 0; j < 8; ++j) {
                    unsigned b = 1u << (i * 8 + j);
                    if (mask & b) continue;
                    int tloc = (j < 4) ? (tt4 + j) : (128 + tt4 + (j - 4));
                    u64 key = ((u64)__float_as_uint(acc[i][j]) << 16) |
                              (u64)(unsigned)(tbase + tloc);
                    if (key < kv[i]) {
                        unsigned pos = atomicAdd(&cnt[tq4 + i], 1u);
                        if (pos < FCAP) { buf[tq4 + i][pos] = key; mask |= b; }
                    }
                }
            }
            __syncthreads();
            if (tid < QT) {
                unsigned n = cnt[tid];
                unsigned m = n < FCAP ? n : FCAP;
                for (unsigned e = 0; e < m; ++e) {
                    u64 key = buf[tid][e];
                    if (key < topk[tid][KNN - 1]) {
                        int p = KNN - 1;
                        while (p > 0 && topk[tid][p - 1] > key) {
                            topk[tid][p] = topk[tid][p - 1];
                            --p;
                        }
                        topk[tid][p] = key;
                    }
                }
                kth64[tid] = topk[tid][KNN - 1];
                if (n > FCAP) againF = 1;
                cnt[tid] = 0u;
            }
            __syncthreads();
            int go = againF;
            __syncthreads();
            if (tid == 0) againF = 0;
            if (!go) break;
            __syncthreads();
        }
    }

    __syncthreads();
    for (int i = tid; i < QT * KNN; i += 256) {
        int q = i >> 5, k = i & 31;
        cand[((size_t)(q0 + q) * NS + blockIdx.y) * KNN + k] = topk[q][k];
    }
}

__global__ void knn_merge(const u64* __restrict__ cand,
                          const int* __restrict__ y_train, int* __restrict__ out) {
    __shared__ u64 keys[NS * KNN];
    __shared__ u64 top[KNN];
    __shared__ int counts[NC];
    int q = blockIdx.x;
    for (int i = threadIdx.x; i < NS * KNN; i += 64)
        keys[i] = cand[(size_t)q * NS * KNN + i];
    for (int i = threadIdx.x; i < NC; i += 64) counts[i] = 0;
    if (threadIdx.x < KNN) top[threadIdx.x] = ~0ULL;
    __syncthreads();

    if (threadIdx.x == 0) {
        for (int s = 0; s < NS; ++s) {
            for (int j = 0; j < KNN; ++j) {
                u64 key = keys[s * KNN + j];
                if (key >= top[KNN - 1]) break;
                int p = KNN - 1;
                while (p > 0 && top[p - 1] > key) { top[p] = top[p - 1]; --p; }
                top[p] = key;
            }
        }
        for (int k = 0; k < KNN; ++k) {
            int idx = (int)(top[k] & 0xFFFF);
            counts[y_train[idx]]++;
        }
        int bestc = counts[0], bestl = 0;
        for (int c = 1; c < NC; ++c)
            if (counts[c] > bestc) { bestc = counts[c]; bestl = c; }
        out[q] = bestl;
    }
}

extern "C" void kernel_launch(void* const* d_in, const int* in_sizes, int n_in,
                              void* d_out, int out_size, void* d_ws, size_t ws_size,
                              hipStream_t stream) {
    const float* Xq = (const float*)d_in[0];   // [2048, 512]
    const float* Xt = (const float*)d_in[1];   // [65536, 512]
    const int*   y  = (const int*)d_in[2];     // [65536]
    int* out = (int*)d_out;                    // [2048] int32

    float* t2 = (float*)d_ws;                                   // 256 KB
    float* q2 = t2 + NT;                                        // 8 KB
    u64* cand = (u64*)(q2 + NQ);                                // 16.8 MB (fallback paths)
    u32* seed = (u32*)(cand + (size_t)NQ * NS * KNN);           // 8 KB
    u16* Qh = (u16*)(seed + NQ);                                // 2 MB
    u16* Ql = Qh + (size_t)NQ * DIM;                            // 2 MB
    u16* Th = Ql + (size_t)NQ * DIM;                            // 64 MB
    u16* Tl = Th + (size_t)NT * DIM;                            // 64 MB
    u64* glist = (u64*)(Tl + (size_t)NT * DIM);                 // 64 MB (filter path)
    u32* gcnt  = (u32*)(glist + (size_t)NQ * GCAP);             // 8 KB
    float* Dpre = (float*)glist;                                // 16 MB, aliases glist (dead before gemm)

    const size_t need = (size_t)(NT + NQ) * 4
                      + (size_t)NQ * NS * KNN * 8
                      + (size_t)NQ * 4
                      + 2 * ((size_t)NQ * DIM + (size_t)NT * DIM) * 2;  // ~148.3 MB
    const bool use_mfma = ws_size >= need;
    const bool use_filter = ws_size >= need + (size_t)NQ * GCAP * 8 + (size_t)NQ * 4;  // +64 MB

    norm_kernel<<<NT / 4, 256, 0, stream>>>(Xt, t2, NT);
    norm_kernel<<<NQ / 4, 256, 0, stream>>>(Xq, q2, NQ);
    if (use_mfma && use_filter) {
        split_kernel<<<(NQ * DIM / 4 + 255) / 256, 256, 0, stream>>>(Xq, Qh, Ql, NQ * DIM / 4);
        split_kernel<<<(NT * DIM / 4 + 255) / 256, 256, 0, stream>>>(Xt, Th, Tl, NT * DIM / 4);
        knn_pre<<<dim3(NQ / PQT, NTPRE / PSLICE), 256, 0, stream>>>(Xq, Xt, q2, t2, Dpre);
        seed_topk<<<NQ, 64, 0, stream>>>(Dpre, seed);
        hipMemsetAsync(gcnt, 0, NQ * sizeof(u32), stream);
        gemm_filter<<<dim3(NQ / 128, NT / 256), 512, 0, stream>>>(
            Qh, Ql, Th, Tl, q2, t2, seed, gcnt, glist);
        knn_topk<<<NQ, 64, 0, stream>>>(glist, gcnt, y, out);
    } else if (use_mfma) {
        hipMemsetAsync(seed, 0xFF, NQ * sizeof(u32), stream);
        split_kernel<<<(NQ * DIM / 4 + 255) / 256, 256, 0, stream>>>(Xq, Qh, Ql, NQ * DIM / 4);
        split_kernel<<<(NT * DIM / 4 + 255) / 256, 256, 0, stream>>>(Xt, Th, Tl, NT * DIM / 4);
        knn_prepass<<<dim3(NQ / PQT, NTPRE / PSLICE), 256, 0, stream>>>(Xq, Xt, q2, t2, seed);
        knn_mfma<<<dim3(NT / MSLICE, NQ / MQT), 512, 0, stream>>>(Qh, Ql, Th, Tl, q2, t2, seed, cand);
        knn_merge<<<NQ, 64, 0, stream>>>(cand, y, out);
    } else {
        knn_part<<<dim3(NQ / QT, NS), 256, 0, stream>>>(Xq, Xt, q2, t2, cand);
        knn_merge<<<NQ, 64, 0, stream>>>(cand, y, out);
    }
}

// Round 10
// 1102.971 us; speedup vs baseline: 1.1150x; 1.1150x over previous
//
#include <hip/hip_runtime.h>
#include <hip/hip_bf16.h>
#include <stdint.h>

typedef unsigned long long u64;
typedef unsigned int u32;
typedef unsigned short u16;
typedef __attribute__((ext_vector_type(8))) short short8;
typedef __attribute__((ext_vector_type(16))) float float16;

#define NQ 2048
#define NT 65536
#define DIM 512
#define KNN 32
#define NC 100
#define NS 32               // slices (fallback paths), cand[q][slice][k]

// ---- fallback (R2) params ----
#define QT 32
#define SLICE (NT / NS)     // 2048
#define TT 256
#define KK 16
#define FCAP 32

// ---- prepass params (fp32, trains 0..2047 subsample) ----
#define PQT 32
#define PTT 256
#define PSLICE 512
#define NTPRE 2048

// ---- fused-mfma fallback params (R4, proven) ----
#define MQT 128
#define MTT 128
#define MBK 32
#define MSLICE 2048
#define SCAP 16
#define NTILES 256

// ---- filter-path params (R6, proven) ----
#define GCAP 4096           // per-query candidate capacity; exact-2048 seed admits ~1024±180 (17 sigma)

// ---- R10 gemm_filter geometry: 256q x 256t, 2-buffer ----
#define G2BUF 32768         // u16 elems per buffer (64 KB): Ah@0 Al@8192 Bh@16384 Bl@24576

// ---------------- row-norm kernel ----------------
__global__ void norm_kernel(const float* __restrict__ X, float* __restrict__ out, int nrows) {
    int row = blockIdx.x * 4 + (threadIdx.x >> 6);
    int lane = threadIdx.x & 63;
    if (row >= nrows) return;
    const float4* p = (const float4*)(X + (size_t)row * DIM);
    float4 a = p[lane];
    float4 b = p[lane + 64];
    float s = a.x*a.x + a.y*a.y + a.z*a.z + a.w*a.w
            + b.x*b.x + b.y*b.y + b.z*b.z + b.w*b.w;
    #pragma unroll
    for (int off = 32; off > 0; off >>= 1) s += __shfl_down(s, off, 64);
    if (lane == 0) out[row] = s;
}

// ---------------- bf16 hi/lo split ----------------
__global__ void split_kernel(const float* __restrict__ X, u16* __restrict__ H,
                             u16* __restrict__ L, int n4) {
    int i = blockIdx.x * 256 + threadIdx.x;
    if (i >= n4) return;
    float4 v = ((const float4*)X)[i];
    float f[4] = {v.x, v.y, v.z, v.w};
    u16 hh[4], ll[4];
    #pragma unroll
    for (int j = 0; j < 4; ++j) {
        union { __hip_bfloat16 b; u16 u; } cv;
        cv.b = __float2bfloat16(f[j]);
        hh[j] = cv.u;
        float hf = __bfloat162float(cv.b);
        cv.b = __float2bfloat16(f[j] - hf);
        ll[j] = cv.u;
    }
    ((ushort4*)H)[i] = make_ushort4(hh[0], hh[1], hh[2], hh[3]);
    ((ushort4*)L)[i] = make_ushort4(ll[0], ll[1], ll[2], ll[3]);
}

// ---------------- knn_pre: fp32 distances for trains 0..2047, written to Dpre --------------
__launch_bounds__(256, 2)
__global__ void knn_pre(const float* __restrict__ Xq, const float* __restrict__ Xt,
                        const float* __restrict__ q2, const float* __restrict__ t2,
                        float* __restrict__ Dpre) {
    __shared__ float sQ[KK][PQT];
    __shared__ float sT[KK][PTT];

    const int tid = threadIdx.x;
    const int q0 = blockIdx.x * PQT;
    const int t0p = blockIdx.y * PSLICE;
    const int tq4 = (tid >> 5) * 4;
    const int tt4 = (tid & 31) * 4;
    const int pg = tid & 63;
    const int kg = tid >> 6;
    const int qp = tid & 31;
    const int kq = tid >> 5;

    float qq[4];
    #pragma unroll
    for (int i = 0; i < 4; ++i) qq[i] = q2[q0 + tq4 + i];

    #pragma unroll 1
    for (int chunk = 0; chunk < PSLICE / PTT; ++chunk) {
        const int tbase = t0p + chunk * PTT;
        float acc[4][8];
        #pragma unroll
        for (int i = 0; i < 4; ++i)
            #pragma unroll
            for (int j = 0; j < 8; ++j) acc[i][j] = 0.f;

        #pragma unroll 1
        for (int k0 = 0; k0 < DIM; k0 += KK) {
            __syncthreads();   // protects sQ/sT reuse
            {
                const float* Tp = Xt + (size_t)(tbase + pg * 4) * DIM + k0 + kg * 4;
                float4 r0 = *(const float4*)(Tp);
                float4 r1 = *(const float4*)(Tp + DIM);
                float4 r2 = *(const float4*)(Tp + 2 * DIM);
                float4 r3 = *(const float4*)(Tp + 3 * DIM);
                *(float4*)&sT[kg * 4 + 0][pg * 4] = make_float4(r0.x, r1.x, r2.x, r3.x);
                *(float4*)&sT[kg * 4 + 1][pg * 4] = make_float4(r0.y, r1.y, r2.y, r3.y);
                *(float4*)&sT[kg * 4 + 2][pg * 4] = make_float4(r0.z, r1.z, r2.z, r3.z);
                *(float4*)&sT[kg * 4 + 3][pg * 4] = make_float4(r0.w, r1.w, r2.w, r3.w);
            }
            {
                float2 v = *(const float2*)(Xq + (size_t)(q0 + qp) * DIM + k0 + kq * 2);
                sQ[kq * 2 + 0][qp] = v.x;
                sQ[kq * 2 + 1][qp] = v.y;
            }
            __syncthreads();
            #pragma unroll
            for (int k = 0; k < KK; ++k) {
                float4 qv = *(const float4*)&sQ[k][tq4];
                float4 ta = *(const float4*)&sT[k][tt4];
                float4 tb = *(const float4*)&sT[k][128 + tt4];
                float qa[4] = {qv.x, qv.y, qv.z, qv.w};
                float tv[8] = {ta.x, ta.y, ta.z, ta.w, tb.x, tb.y, tb.z, tb.w};
                #pragma unroll
                for (int i = 0; i < 4; ++i)
                    #pragma unroll
                    for (int j = 0; j < 8; ++j)
                        acc[i][j] = fmaf(qa[i], tv[j], acc[i][j]);
            }
        }

        float t2v[8];
        #pragma unroll
        for (int j = 0; j < 4; ++j) {
            t2v[j]     = t2[tbase + tt4 + j];
            t2v[4 + j] = t2[tbase + 128 + tt4 + j];
        }
        #pragma unroll
        for (int i = 0; i < 4; ++i) {
            float4 lo, hi;
            lo.x = fmaxf(qq[i] - 2.f * acc[i][0] + t2v[0], 0.f);
            lo.y = fmaxf(qq[i] - 2.f * acc[i][1] + t2v[1], 0.f);
            lo.z = fmaxf(qq[i] - 2.f * acc[i][2] + t2v[2], 0.f);
            lo.w = fmaxf(qq[i] - 2.f * acc[i][3] + t2v[3], 0.f);
            hi.x = fmaxf(qq[i] - 2.f * acc[i][4] + t2v[4], 0.f);
            hi.y = fmaxf(qq[i] - 2.f * acc[i][5] + t2v[5], 0.f);
            hi.z = fmaxf(qq[i] - 2.f * acc[i][6] + t2v[6], 0.f);
            hi.w = fmaxf(qq[i] - 2.f * acc[i][7] + t2v[7], 0.f);
            *(float4*)&Dpre[(size_t)(q0 + tq4 + i) * NTPRE + tbase + tt4] = lo;
            *(float4*)&Dpre[(size_t)(q0 + tq4 + i) * NTPRE + tbase + 128 + tt4] = hi;
        }
    }
}

// ---------------- seed_topk: exact 32nd-smallest of Dpre row -> seed[q] -------------------
__launch_bounds__(64)
__global__ void seed_topk(const float* __restrict__ Dpre, u32* __restrict__ seed) {
    __shared__ u64 ll[64][KNN + 1];   // pad: stride 33 u64 -> 2-way banks only
    const int q = blockIdx.x;
    const int lane = threadIdx.x;
    #pragma unroll
    for (int j = 0; j <= KNN; ++j) ll[lane][j] = ~0ULL;
    const float* src = Dpre + (size_t)q * NTPRE;
    u64 kth = ~0ULL;
    for (int i = lane; i < NTPRE; i += 64) {
        u64 key = (u64)__float_as_uint(src[i]);
        if (key < kth) {
            int p = KNN - 1;
            while (p > 0 && ll[lane][p - 1] > key) { ll[lane][p] = ll[lane][p - 1]; --p; }
            ll[lane][p] = key;
            kth = ll[lane][KNN - 1];
        }
    }
    __syncthreads();
    int ptr = 0;
    u64 cur = ll[lane][0];
    u64 m = 0;
    for (int it = 0; it < KNN; ++it) {
        m = cur;
        #pragma unroll
        for (int off = 32; off > 0; off >>= 1) {
            u64 o = __shfl_xor(m, off, 64);
            m = (o < m) ? o : m;
        }
        u64 got = __ballot(cur == m);
        int w = __ffsll(got) - 1;
        if (lane == w) { ++ptr; cur = (ptr < KNN) ? ll[lane][ptr] : ~0ULL; }
    }
    if (lane == 0) seed[q] = (u32)m;   // 32nd smallest dist bits (exact over 2048 subsample)
}

// ---------------- async global->LDS 16B ----------------
__device__ __forceinline__ void gld16(const void* g, void* l) {
    __builtin_amdgcn_global_load_lds(
        (const __attribute__((address_space(1))) u32*)g,
        (__attribute__((address_space(3))) u32*)l, 16, 0, 0);
}

// ---------------- gemm_filter: 256q x 256t, 2-buffer pipeline (R10) -----------------------
// THEORY: R7/R8/R9 all ~800 us regardless of schedule -> L3-BW-bound on STAGED bytes
// (3.1 GB @ ~4 TB/s). Fix = cut traffic: BM=256 halves B traffic (T panel read NQ/256=8x
// instead of 16x): A 1.05 GB + B 1.05 GB = 2.1 GB (1.5x cut). 512 thr, 8 waves, wave-tile
// 64m x 128n (acc[2][4]). LDS 2x64KB + 3KB = 131 KB, 1 block/CU. Schedule: R8-style
// issue-early dbuf (48 MFMA/wave compute phase covers load latency). XCD colocation
// (bijective 2048 = 8*256): co-residents share 4 T-tiles x 8 q-tiles.
__launch_bounds__(512, 1)
__global__ void gemm_filter(const u16* __restrict__ Qh, const u16* __restrict__ Ql,
                            const u16* __restrict__ Th, const u16* __restrict__ Tl,
                            const float* __restrict__ q2, const float* __restrict__ t2,
                            const u32* __restrict__ seed,
                            u32* __restrict__ gcnt, u64* __restrict__ glist) {
    __shared__ __align__(16) u16 tiles[2][G2BUF];  // Ah[256][32]@0 Al@8192 Bh[256][32]@16384 Bl@24576
    __shared__ float sQ2L[256];
    __shared__ float sT2L[256];
    __shared__ u32 sSeed[256];

    const int tid = threadIdx.x;
    const int lane = tid & 63;
    const int wid = tid >> 6;             // 0..7
    const int bid = blockIdx.x + (int)(gridDim.x * blockIdx.y);   // x fastest (gridDim.x=8)
    const int wg  = ((bid & 7) << 8) + (bid >> 3);                // XCD-colocating remap (2048=8*256)
    const int q0g = (wg & 7) * 256;       // query base
    const int tb  = (wg >> 3) * 256;      // train base (32 consecutive y-tiles per XCD)
    const int m_off = (wid >> 1) * 64;    // 0,64,128,192
    const int n_off = (wid & 1) * 128;    // 0,128
    const int swz = ((lane >> 1) & 3) << 3;
    const int l4r = lane >> 2;
    const int l4c = (((lane & 3) ^ ((lane >> 3) & 3)) * 8);

    if (tid < 256) {
        sQ2L[tid] = q2[q0g + tid];
        sSeed[tid] = seed[q0g + tid] + 256u;   // admission threshold (+ulp margin)
        sT2L[tid] = t2[tb + tid];
    }

    float16 acc[2][4];
    #pragma unroll
    for (int mi = 0; mi < 2; ++mi)
        #pragma unroll
        for (int nj = 0; nj < 4; ++nj) acc[mi][nj] = (float16)(0.0f);

    // stage one 64 KB tile: 64 units of (16 rows x 32 elems); wave w takes units w+8*s8
    // (exactly 8 gld16 per wave). Units: [0,16) Ah, [16,32) Al, [32,48) Bh, [48,64) Bl.
    #define STAGE_TILE(BUF, K0)                                                         \
        do {                                                                            \
            _Pragma("unroll")                                                           \
            for (int s8 = 0; s8 < 8; ++s8) {                                            \
                const int ii = wid + s8 * 8;                                            \
                const u16* P; int rb, off;                                              \
                if (ii < 16)      { P = Qh; rb = q0g + ii * 16;        off = ii * 512; }          \
                else if (ii < 32) { P = Ql; rb = q0g + (ii - 16) * 16; off = 8192 + (ii - 16) * 512; } \
                else if (ii < 48) { P = Th; rb = tb + (ii - 32) * 16;  off = 16384 + (ii - 32) * 512; } \
                else              { P = Tl; rb = tb + (ii - 48) * 16;  off = 24576 + (ii - 48) * 512; } \
                gld16(P + (size_t)(rb + l4r) * DIM + (K0) + l4c,                        \
                      (u16*)tiles[BUF] + off);                                          \
            }                                                                           \
        } while (0)

    STAGE_TILE(0, 0);
    __syncthreads();   // prologue drain: tile 0 ready, epilogue arrays visible (vmcnt=0)

    int cur = 0;
    #pragma unroll 1
    for (int t = 0; t < DIM / MBK; ++t) {          // 16 windows
        if (t + 1 < DIM / MBK) STAGE_TILE(cur ^ 1, (t + 1) * MBK);   // issue early

        const u16* pAh = tiles[cur];
        const u16* pAl = pAh + 8192;
        const u16* pBh = pAh + 16384;
        const u16* pBl = pAh + 24576;
        __builtin_amdgcn_s_setprio(1);
        #pragma unroll
        for (int s = 0; s < 2; ++s) {
            const int kb = (s * 16 + (lane >> 5) * 8) ^ swz;
            short8 ah[2], al[2], bh[4], bl[4];
            #pragma unroll
            for (int mi = 0; mi < 2; ++mi) {
                int row = m_off + mi * 32 + (lane & 31);
                ah[mi] = *(const short8*)(const void*)&pAh[row * 32 + kb];
                al[mi] = *(const short8*)(const void*)&pAl[row * 32 + kb];
            }
            #pragma unroll
            for (int nj = 0; nj < 4; ++nj) {
                int row = n_off + nj * 32 + (lane & 31);
                bh[nj] = *(const short8*)(const void*)&pBh[row * 32 + kb];
                bl[nj] = *(const short8*)(const void*)&pBl[row * 32 + kb];
            }
            #pragma unroll
            for (int mi = 0; mi < 2; ++mi)
                #pragma unroll
                for (int nj = 0; nj < 4; ++nj) {
                    acc[mi][nj] = __builtin_amdgcn_mfma_f32_32x32x16_bf16(ah[mi], bh[nj], acc[mi][nj], 0, 0, 0);
                    acc[mi][nj] = __builtin_amdgcn_mfma_f32_32x32x16_bf16(ah[mi], bl[nj], acc[mi][nj], 0, 0, 0);
                    acc[mi][nj] = __builtin_amdgcn_mfma_f32_32x32x16_bf16(al[mi], bh[nj], acc[mi][nj], 0, 0, 0);
                }
        }
        __builtin_amdgcn_s_setprio(0);
        // next tile's loads had the whole 48-MFMA compute phase in flight -> residual wait
        asm volatile("s_waitcnt vmcnt(0)" ::: "memory");
        __builtin_amdgcn_s_barrier();
        __builtin_amdgcn_sched_barrier(0);
        cur ^= 1;
    }
    #undef STAGE_TILE

    // epilogue: rare filtered push (frag map: col=lane&31, row=(r&3)+8*(r>>2)+4*(lane>>5))
    #pragma unroll
    for (int mi = 0; mi < 2; ++mi)
        #pragma unroll
        for (int nj = 0; nj < 4; ++nj) {
            const int tcol_l = n_off + nj * 32 + (lane & 31);
            const float t2v = sT2L[tcol_l];
            #pragma unroll
            for (int r = 0; r < 16; ++r) {
                const int qrow_l = m_off + mi * 32 + (r & 3) + 8 * (r >> 2) + 4 * (lane >> 5);
                float d = fmaxf(sQ2L[qrow_l] - 2.0f * acc[mi][nj][r] + t2v, 0.0f);
                if (__float_as_uint(d) <= sSeed[qrow_l]) {
                    const int q = q0g + qrow_l;
                    u32 pos = atomicAdd(&gcnt[q], 1u);
                    if (pos < GCAP)
                        glist[(size_t)q * GCAP + pos] =
                            ((u64)__float_as_uint(d) << 16) | (u64)(u32)(tb + tcol_l);
                }
            }
        }
}

// ---------------- knn_topk: exact top-32 over candidate list + vote -> out ----------------
__launch_bounds__(64)
__global__ void knn_topk(const u64* __restrict__ glist, const u32* __restrict__ gcnt,
                         const int* __restrict__ y_train, int* __restrict__ out) {
    __shared__ u64 ll[64][KNN + 1];
    __shared__ u64 fin[KNN];
    __shared__ int counts[NC];
    const int q = blockIdx.x;
    const int lane = threadIdx.x;
    #pragma unroll
    for (int j = 0; j <= KNN; ++j) ll[lane][j] = ~0ULL;
    for (int i = lane; i < NC; i += 64) counts[i] = 0;
    u32 n = gcnt[q]; if (n > GCAP) n = GCAP;
    const u64* src = glist + (size_t)q * GCAP;
    u64 kth = ~0ULL;
    for (u32 i = lane; i < n; i += 64) {
        u64 key = src[i];
        if (key < kth) {
            int p = KNN - 1;
            while (p > 0 && ll[lane][p - 1] > key) { ll[lane][p] = ll[lane][p - 1]; --p; }
            ll[lane][p] = key;
            kth = ll[lane][KNN - 1];
        }
    }
    __syncthreads();
    int ptr = 0;
    u64 cur = ll[lane][0];
    for (int it = 0; it < KNN; ++it) {
        u64 m = cur;
        #pragma unroll
        for (int off = 32; off > 0; off >>= 1) {
            u64 o = __shfl_xor(m, off, 64);
            m = (o < m) ? o : m;
        }
        u64 got = __ballot(cur == m);
        int w = __ffsll(got) - 1;
        if (lane == 0) fin[it] = m;
        if (lane == w) { ++ptr; cur = (ptr < KNN) ? ll[lane][ptr] : ~0ULL; }
    }
    __syncthreads();
    if (lane < KNN) {
        int idx = (int)(fin[lane] & 0xFFFF);
        atomicAdd(&counts[y_train[idx]], 1);
    }
    __syncthreads();
    if (lane == 0) {
        int bestc = counts[0], bestl = 0;
        for (int c = 1; c < NC; ++c)
            if (counts[c] > bestc) { bestc = counts[c]; bestl = c; }
        out[q] = bestl;
    }
}

// ================= fallback machinery (R4 fused path + fp32 path), proven =================

__launch_bounds__(256, 2)
__global__ void knn_prepass(const float* __restrict__ Xq, const float* __restrict__ Xt,
                            const float* __restrict__ q2, const float* __restrict__ t2,
                            u32* __restrict__ seed) {
    __shared__ float sQ[KK][PQT];
    __shared__ float sT[KK][PTT];
    __shared__ float sD[PQT][PTT + 1];
    __shared__ u32 topk[PQT][KNN + 1];

    const int tid = threadIdx.x;
    const int q0 = blockIdx.x * PQT;
    const int t0p = blockIdx.y * PSLICE;
    const int tq4 = (tid >> 5) * 4;
    const int tt4 = (tid & 31) * 4;
    const int pg = tid & 63;
    const int kg = tid >> 6;
    const int qp = tid & 31;
    const int kq = tid >> 5;

    for (int i = tid; i < PQT * (KNN + 1); i += 256) ((u32*)topk)[i] = 0xFFFFFFFFu;
    u32 kth = 0xFFFFFFFFu;

    float qq[4];
    #pragma unroll
    for (int i = 0; i < 4; ++i) qq[i] = q2[q0 + tq4 + i];

    #pragma unroll 1
    for (int chunk = 0; chunk < PSLICE / PTT; ++chunk) {
        const int tbase = t0p + chunk * PTT;
        float acc[4][8];
        #pragma unroll
        for (int i = 0; i < 4; ++i)
            #pragma unroll
            for (int j = 0; j < 8; ++j) acc[i][j] = 0.f;

        #pragma unroll 1
        for (int k0 = 0; k0 < DIM; k0 += KK) {
            __syncthreads();
            {
                const float* Tp = Xt + (size_t)(tbase + pg * 4) * DIM + k0 + kg * 4;
                float4 r0 = *(const float4*)(Tp);
                float4 r1 = *(const float4*)(Tp + DIM);
                float4 r2 = *(const float4*)(Tp + 2 * DIM);
                float4 r3 = *(const float4*)(Tp + 3 * DIM);
                *(float4*)&sT[kg * 4 + 0][pg * 4] = make_float4(r0.x, r1.x, r2.x, r3.x);
                *(float4*)&sT[kg * 4 + 1][pg * 4] = make_float4(r0.y, r1.y, r2.y, r3.y);
                *(float4*)&sT[kg * 4 + 2][pg * 4] = make_float4(r0.z, r1.z, r2.z, r3.z);
                *(float4*)&sT[kg * 4 + 3][pg * 4] = make_float4(r0.w, r1.w, r2.w, r3.w);
            }
            {
                float2 v = *(const float2*)(Xq + (size_t)(q0 + qp) * DIM + k0 + kq * 2);
                sQ[kq * 2 + 0][qp] = v.x;
                sQ[kq * 2 + 1][qp] = v.y;
            }
            __syncthreads();
            #pragma unroll
            for (int k = 0; k < KK; ++k) {
                float4 qv = *(const float4*)&sQ[k][tq4];
                float4 ta = *(const float4*)&sT[k][tt4];
                float4 tb = *(const float4*)&sT[k][128 + tt4];
                float qa[4] = {qv.x, qv.y, qv.z, qv.w};
                float tv[8] = {ta.x, ta.y, ta.z, ta.w, tb.x, tb.y, tb.z, tb.w};
                #pragma unroll
                for (int i = 0; i < 4; ++i)
                    #pragma unroll
                    for (int j = 0; j < 8; ++j)
                        acc[i][j] = fmaf(qa[i], tv[j], acc[i][j]);
            }
        }

        #pragma unroll
        for (int i = 0; i < 4; ++i)
            #pragma unroll
            for (int j = 0; j < 8; ++j) {
                int t = (j < 4) ? (tt4 + j) : (128 + tt4 + (j - 4));
                sD[tq4 + i][t] = fmaxf((qq[i] - 2.f * acc[i][j]) + t2[tbase + t], 0.f);
            }
        __syncthreads();

        if (tid < PQT) {
            for (int t = 0; t < PTT; ++t) {
                u32 d = __float_as_uint(sD[tid][t]);
                if (d < kth) {
                    int p = KNN - 1;
                    while (p > 0 && topk[tid][p - 1] > d) {
                        topk[tid][p] = topk[tid][p - 1];
                        --p;
                    }
                    topk[tid][p] = d;
                    kth = topk[tid][KNN - 1];
                }
            }
        }
    }
    if (tid < PQT) atomicMin(&seed[q0 + tid], kth);
}

__device__ __forceinline__ void stage_tile(const u16* __restrict__ Qh, const u16* __restrict__ Ql,
                                           const u16* __restrict__ Th, const u16* __restrict__ Tl,
                                           u16* base, int q0, int tb, int k0, int wid, int lane) {
    const int l4r = lane >> 2;
    const int l4c = (((lane & 3) ^ ((lane >> 3) & 3)) * 8);
    #pragma unroll
    for (int u = 0; u < 4; ++u) {
        const u16* P = (u == 0) ? Qh : (u == 1) ? Ql : (u == 2) ? Th : Tl;
        const int r0 = (u < 2) ? q0 : tb;
        const u16* g = P + (size_t)(r0 + wid * 16 + l4r) * DIM + k0 + l4c;
        gld16(g, base + u * 4096 + wid * 512);
    }
}

__launch_bounds__(512, 1)
__global__ void knn_mfma(const u16* __restrict__ Qh, const u16* __restrict__ Ql,
                         const u16* __restrict__ Th, const u16* __restrict__ Tl,
                         const float* __restrict__ q2, const float* __restrict__ t2,
                         const u32* __restrict__ seed, u64* __restrict__ cand) {
    __shared__ __align__(16) u16 tiles[3][16384];
    __shared__ u32 topkD[MQT][KNN + 1];
    __shared__ u16 topkI[MQT][KNN + 1];
    __shared__ u64 sbuf[MQT][SCAP];
    __shared__ u64 kth64[MQT];
    __shared__ u32 cnt[MQT];
    __shared__ float sQ2[MQT];
    __shared__ float sT2[MTT];
    __shared__ int againF;

    const int tid = threadIdx.x;
    const int lane = tid & 63;
    const int wid = tid >> 6;
    const int q0 = blockIdx.y * MQT;
    const int s0 = blockIdx.x * MSLICE;
    const int m_off = (wid >> 2) * 64;
    const int n_off = (wid & 3) * 32;
    const int swz = ((lane >> 1) & 3) << 3;

    for (int i = tid; i < MQT * (KNN + 1); i += 512) {
        ((u32*)topkD)[i] = 0xFFFFFFFFu;
        ((u16*)topkI)[i] = 0xFFFFu;
    }
    u64 seedkey = ~0ULL;
    if (tid < MQT) {
        seedkey = ((u64)seed[q0 + tid] + 1) << 16;
        kth64[tid] = seedkey;
        cnt[tid] = 0u;
        sQ2[tid] = q2[q0 + tid];
    }
    if (tid == 0) againF = 0;

    stage_tile(Qh, Ql, Th, Tl, tiles[0], q0, s0, 0, wid, lane);
    stage_tile(Qh, Ql, Th, Tl, tiles[1], q0, s0, MBK, wid, lane);
    __syncthreads();

    int cb = 0;
    #pragma unroll 1
    for (int chunk = 0; chunk < MSLICE / MTT; ++chunk) {
        const int tb = s0 + chunk * MTT;
        float16 acc[2];
        acc[0] = (float16)(0.0f);
        acc[1] = (float16)(0.0f);

        #pragma unroll 1
        for (int t = 0; t < DIM / MBK; ++t) {
            const int Tn = chunk * 16 + t + 2;
            const bool pf = (Tn < NTILES);
            if (pf) {
                int bn = cb + 2; if (bn >= 3) bn -= 3;
                stage_tile(Qh, Ql, Th, Tl, tiles[bn], q0,
                           s0 + (Tn >> 4) * MTT, (Tn & 15) * MBK, wid, lane);
            }
            const u16* sAh = tiles[cb];
            const u16* sAl = sAh + 4096;
            const u16* sBh = sAh + 8192;
            const u16* sBl = sAh + 12288;
            #pragma unroll
            for (int s = 0; s < 2; ++s) {
                const int kb = (s * 16 + (lane >> 5) * 8) ^ swz;
                short8 ah[2], al[2];
                #pragma unroll
                for (int mi = 0; mi < 2; ++mi) {
                    int row = m_off + mi * 32 + (lane & 31);
                    ah[mi] = *(const short8*)(const void*)&sAh[row * MBK + kb];
                    al[mi] = *(const short8*)(const void*)&sAl[row * MBK + kb];
                }
                int brow = n_off + (lane & 31);
                short8 bh = *(const short8*)(const void*)&sBh[brow * MBK + kb];
                short8 bl = *(const short8*)(const void*)&sBl[brow * MBK + kb];
                #pragma unroll
                for (int mi = 0; mi < 2; ++mi) {
                    acc[mi] = __builtin_amdgcn_mfma_f32_32x32x16_bf16(ah[mi], bh, acc[mi], 0, 0, 0);
                    acc[mi] = __builtin_amdgcn_mfma_f32_32x32x16_bf16(ah[mi], bl, acc[mi], 0, 0, 0);
                    acc[mi] = __builtin_amdgcn_mfma_f32_32x32x16_bf16(al[mi], bh, acc[mi], 0, 0, 0);
                }
            }
            if (pf) asm volatile("s_waitcnt vmcnt(4)" ::: "memory");
            else    asm volatile("s_waitcnt vmcnt(0)" ::: "memory");
            __builtin_amdgcn_s_barrier();
            __builtin_amdgcn_sched_barrier(0);
            ++cb; if (cb >= 3) cb = 0;
        }

        if (tid < MTT) sT2[tid] = t2[tb + tid];
        __syncthreads();
        const float t2r = sT2[n_off + (lane & 31)];
        const int tcol = n_off + (lane & 31);

        u32 mask = 0;
        for (;;) {
            #pragma unroll
            for (int mi = 0; mi < 2; ++mi) {
                #pragma unroll
                for (int r = 0; r < 16; ++r) {
                    const int bit = mi * 16 + r;
                    if ((mask >> bit) & 1) continue;
                    const int qrow = m_off + mi * 32 + (r & 3) + 8 * (r >> 2) + 4 * (lane >> 5);
                    float d = fmaxf(sQ2[qrow] - 2.0f * acc[mi][r] + t2r, 0.0f);
                    u64 key = ((u64)__float_as_uint(d) << 16) | (u64)(u32)(tb + tcol);
                    if (key < kth64[qrow]) {
                        u32 pos = atomicAdd(&cnt[qrow], 1u);
                        if (pos < SCAP) { sbuf[qrow][pos] = key; mask |= (1u << bit); }
                    }
                }
            }
            __syncthreads();
            if (tid < MQT) {
                u32 n = cnt[tid];
                u32 m = n < SCAP ? n : SCAP;
                for (u32 e = 0; e < m; ++e) {
                    u64 key = sbuf[tid][e];
                    u64 last = ((u64)topkD[tid][KNN - 1] << 16) | topkI[tid][KNN - 1];
                    if (key < last) {
                        int p = KNN - 1;
                        while (p > 0) {
                            u64 prev = ((u64)topkD[tid][p - 1] << 16) | topkI[tid][p - 1];
                            if (prev > key) {
                                topkD[tid][p] = topkD[tid][p - 1];
                                topkI[tid][p] = topkI[tid][p - 1];
                                --p;
                            } else break;
                        }
                        topkD[tid][p] = (u32)(key >> 16);
                        topkI[tid][p] = (u16)(key & 0xFFFF);
                    }
                }
                u64 last = ((u64)topkD[tid][KNN - 1] << 16) | topkI[tid][KNN - 1];
                kth64[tid] = last < seedkey ? last : seedkey;
                if (n > SCAP) againF = 1;
                cnt[tid] = 0u;
            }
            __syncthreads();
            int go = againF;
            __syncthreads();
            if (tid == 0) againF = 0;
            if (!go) break;
            __syncthreads();
        }
    }

    __syncthreads();
    for (int i = tid; i < MQT * KNN; i += 512) {
        int q = i >> 5, k = i & 31;
        u64 key = ((u64)topkD[q][k] << 16) | topkI[q][k];
        cand[((size_t)(q0 + q) * NS + blockIdx.x) * KNN + k] = key;
    }
}

__launch_bounds__(256, 4)
__global__ void knn_part(const float* __restrict__ Xq, const float* __restrict__ Xt,
                         const float* __restrict__ q2, const float* __restrict__ t2,
                         u64* __restrict__ cand) {
    __shared__ float sQ[KK][QT];
    __shared__ float sT[KK][TT];
    __shared__ u64 topk[QT][KNN];
    __shared__ u64 buf[QT][FCAP];
    __shared__ u64 kth64[QT];
    __shared__ u32 cnt[QT];
    __shared__ int againF;

    const int tid = threadIdx.x;
    const int q0 = blockIdx.x * QT;
    const int t0 = blockIdx.y * SLICE;
    const int tq4 = (tid >> 5) * 4;
    const int tt4 = (tid & 31) * 4;
    const int pg = tid & 63;
    const int kg = tid >> 6;
    const int qp = tid & 31;
    const int kq = tid >> 5;

    for (int i = tid; i < QT * KNN; i += 256) ((u64*)topk)[i] = ~0ULL;
    if (tid < QT) { kth64[tid] = ~0ULL; cnt[tid] = 0u; }
    if (tid == 0) againF = 0;

    float qq[4];
    #pragma unroll
    for (int i = 0; i < 4; ++i) qq[i] = q2[q0 + tq4 + i];

    #pragma unroll 1
    for (int chunk = 0; chunk < SLICE / TT; ++chunk) {
        const int tbase = t0 + chunk * TT;
        float acc[4][8];
        #pragma unroll
        for (int i = 0; i < 4; ++i)
            #pragma unroll
            for (int j = 0; j < 8; ++j) acc[i][j] = 0.f;

        #pragma unroll 1
        for (int k0 = 0; k0 < DIM; k0 += KK) {
            __syncthreads();
            {
                const float* Tp = Xt + (size_t)(tbase + pg * 4) * DIM + k0 + kg * 4;
                float4 r0 = *(const float4*)(Tp);
                float4 r1 = *(const float4*)(Tp + DIM);
                float4 r2 = *(const float4*)(Tp + 2 * DIM);
                float4 r3 = *(const float4*)(Tp + 3 * DIM);
                *(float4*)&sT[kg * 4 + 0][pg * 4] = make_float4(r0.x, r1.x, r2.x, r3.x);
                *(float4*)&sT[kg * 4 + 1][pg * 4] = make_float4(r0.y, r1.y, r2.y, r3.y);
                *(float4*)&sT[kg * 4 + 2][pg * 4] = make_float4(r0.z, r1.z, r2.z, r3.z);
                *(float4*)&sT[kg * 4 + 3][pg * 4] = make_float4(r0.w, r1.w, r2.w, r3.w);
            }
            {
                float2 v = *(const float2*)(Xq + (size_t)(q0 + qp) * DIM + k0 + kq * 2);
                sQ[kq * 2 + 0][qp] = v.x;
                sQ[kq * 2 + 1][qp] = v.y;
            }
            __syncthreads();
            #pragma unroll
            for (int k = 0; k < KK; ++k) {
                float4 qv = *(const float4*)&sQ[k][tq4];
                float4 ta = *(const float4*)&sT[k][tt4];
                float4 tb = *(const float4*)&sT[k][128 + tt4];
                float qa[4] = {qv.x, qv.y, qv.z, qv.w};
                float tv[8] = {ta.x, ta.y, ta.z, ta.w, tb.x, tb.y, tb.z, tb.w};
                #pragma unroll
                for (int i = 0; i < 4; ++i)
                    #pragma unroll
                    for (int j = 0; j < 8; ++j)
                        acc[i][j] = fmaf(qa[i], tv[j], acc[i][j]);
            }
        }

        float t2v[8];
        #pragma unroll
        for (int j = 0; j < 4; ++j) {
            t2v[j]     = t2[tbase + tt4 + j];
            t2v[4 + j] = t2[tbase + 128 + tt4 + j];
        }
        #pragma unroll
        for (int i = 0; i < 4; ++i)
            #pragma unroll
            for (int j = 0; j < 8; ++j)
                acc[i][j] = fmaxf((qq[i] - 2.f * acc[i][j]) + t2v[j], 0.f);

        unsigned mask = 0;
        for (;;) {
            u64 kv[4];
            #pragma unroll
            for (int i = 0; i < 4; ++i) kv[i] = kth64[tq4 + i];
            #pragma unroll
            for (int i = 0; i < 4; ++i) {
                #pragma unroll
                for (int j = 0; j < 8; ++j) {
                    unsigned b = 1u << (i * 8 + j);
                    if (mask & b) continue;
                    int tloc = (j < 4) ? (tt4 + j) : (128 + tt4 + (j - 4));
                    u64 key = ((u64)__float_as_uint(acc[i][j]) << 16) |
                              (u64)(unsigned)(tbase + tloc);
                    if (key < kv[i]) {
                        unsigned pos = atomicAdd(&cnt[tq4 + i], 1u);
                        if (pos < FCAP) { buf[tq4 + i][pos] = key; mask |= b; }
                    }
                }
            }
            __syncthreads();
            if (tid < QT) {
                unsigned n = cnt[tid];
                unsigned m = n < FCAP ? n : FCAP;
                for (unsigned e = 0; e < m; ++e) {
                    u64 key = buf[tid][e];
                    if (key < topk[tid][KNN - 1]) {
                        int p = KNN - 1;
                        while (p > 0 && topk[tid][p - 1] > key) {
                            topk[tid][p] = topk[tid][p - 1];
                            --p;
                        }
                        topk[tid][p] = key;
                    }
                }
                kth64[tid] = topk[tid][KNN - 1];
                if (n > FCAP) againF = 1;
                cnt[tid] = 0u;
            }
            __syncthreads();
            int go = againF;
            __syncthreads();
            if (tid == 0) againF = 0;
            if (!go) break;
            __syncthreads();
        }
    }

    __syncthreads();
    for (int i = tid; i < QT * KNN; i += 256) {
        int q = i >> 5, k = i & 31;
        cand[((size_t)(q0 + q) * NS + blockIdx.y) * KNN + k] = topk[q][k];
    }
}

__global__ void knn_merge(const u64* __restrict__ cand,
                          const int* __restrict__ y_train, int* __restrict__ out) {
    __shared__ u64 keys[NS * KNN];
    __shared__ u64 top[KNN];
    __shared__ int counts[NC];
    int q = blockIdx.x;
    for (int i = threadIdx.x; i < NS * KNN; i += 64)
        keys[i] = cand[(size_t)q * NS * KNN + i];
    for (int i = threadIdx.x; i < NC; i += 64) counts[i] = 0;
    if (threadIdx.x < KNN) top[threadIdx.x] = ~0ULL;
    __syncthreads();

    if (threadIdx.x == 0) {
        for (int s = 0; s < NS; ++s) {
            for (int j = 0; j < KNN; ++j) {
                u64 key = keys[s * KNN + j];
                if (key >= top[KNN - 1]) break;
                int p = KNN - 1;
                while (p > 0 && top[p - 1] > key) { top[p] = top[p - 1]; --p; }
                top[p] = key;
            }
        }
        for (int k = 0; k < KNN; ++k) {
            int idx = (int)(top[k] & 0xFFFF);
            counts[y_train[idx]]++;
        }
        int bestc = counts[0], bestl = 0;
        for (int c = 1; c < NC; ++c)
            if (counts[c] > bestc) { bestc = counts[c]; bestl = c; }
        out[q] = bestl;
    }
}

extern "C" void kernel_launch(void* const* d_in, const int* in_sizes, int n_in,
                              void* d_out, int out_size, void* d_ws, size_t ws_size,
                              hipStream_t stream) {
    const float* Xq = (const float*)d_in[0];   // [2048, 512]
    const float* Xt = (const float*)d_in[1];   // [65536, 512]
    const int*   y  = (const int*)d_in[2];     // [65536]
    int* out = (int*)d_out;                    // [2048] int32

    float* t2 = (float*)d_ws;                                   // 256 KB
    float* q2 = t2 + NT;                                        // 8 KB
    u64* cand = (u64*)(q2 + NQ);                                // 16.8 MB (fallback paths)
    u32* seed = (u32*)(cand + (size_t)NQ * NS * KNN);           // 8 KB
    u16* Qh = (u16*)(seed + NQ);                                // 2 MB
    u16* Ql = Qh + (size_t)NQ * DIM;                            // 2 MB
    u16* Th = Ql + (size_t)NQ * DIM;                            // 64 MB
    u16* Tl = Th + (size_t)NT * DIM;                            // 64 MB
    u64* glist = (u64*)(Tl + (size_t)NT * DIM);                 // 64 MB (filter path)
    u32* gcnt  = (u32*)(glist + (size_t)NQ * GCAP);             // 8 KB
    float* Dpre = (float*)glist;                                // 16 MB, aliases glist (dead before gemm)

    const size_t need = (size_t)(NT + NQ) * 4
                      + (size_t)NQ * NS * KNN * 8
                      + (size_t)NQ * 4
                      + 2 * ((size_t)NQ * DIM + (size_t)NT * DIM) * 2;  // ~148.3 MB
    const bool use_mfma = ws_size >= need;
    const bool use_filter = ws_size >= need + (size_t)NQ * GCAP * 8 + (size_t)NQ * 4;  // +64 MB

    norm_kernel<<<NT / 4, 256, 0, stream>>>(Xt, t2, NT);
    norm_kernel<<<NQ / 4, 256, 0, stream>>>(Xq, q2, NQ);
    if (use_mfma && use_filter) {
        split_kernel<<<(NQ * DIM / 4 + 255) / 256, 256, 0, stream>>>(Xq, Qh, Ql, NQ * DIM / 4);
        split_kernel<<<(NT * DIM / 4 + 255) / 256, 256, 0, stream>>>(Xt, Th, Tl, NT * DIM / 4);
        knn_pre<<<dim3(NQ / PQT, NTPRE / PSLICE), 256, 0, stream>>>(Xq, Xt, q2, t2, Dpre);
        seed_topk<<<NQ, 64, 0, stream>>>(Dpre, seed);
        hipMemsetAsync(gcnt, 0, NQ * sizeof(u32), stream);
        gemm_filter<<<dim3(NQ / 256, NT / 256), 512, 0, stream>>>(
            Qh, Ql, Th, Tl, q2, t2, seed, gcnt, glist);
        knn_topk<<<NQ, 64, 0, stream>>>(glist, gcnt, y, out);
    } else if (use_mfma) {
        hipMemsetAsync(seed, 0xFF, NQ * sizeof(u32), stream);
        split_kernel<<<(NQ * DIM / 4 + 255) / 256, 256, 0, stream>>>(Xq, Qh, Ql, NQ * DIM / 4);
        split_kernel<<<(NT * DIM / 4 + 255) / 256, 256, 0, stream>>>(Xt, Th, Tl, NT * DIM / 4);
        knn_prepass<<<dim3(NQ / PQT, NTPRE / PSLICE), 256, 0, stream>>>(Xq, Xt, q2, t2, seed);
        knn_mfma<<<dim3(NT / MSLICE, NQ / MQT), 512, 0, stream>>>(Qh, Ql, Th, Tl, q2, t2, seed, cand);
        knn_merge<<<NQ, 64, 0, stream>>>(cand, y, out);
    } else {
        knn_part<<<dim3(NQ / QT, NS), 256, 0, stream>>>(Xq, Xt, q2, t2, cand);
        knn_merge<<<NQ, 64, 0, stream>>>(cand, y, out);
    }
}